// Round 2
// baseline (334.137 us; speedup 1.0000x reference)
//
#include <hip/hip_runtime.h>

// Problem constants (fixed by reference setup_inputs)
#define BATCH 8
#define NPTS  4096   // N == M == 4096
#define KD    64
#define MQ    4      // m-strips: each block walks 1024 cols = 8 tiles of 128
#define WALK  8
#define FINF  3.0e38f

typedef float f32x4 __attribute__((ext_vector_type(4)));
typedef float f32x2 __attribute__((ext_vector_type(2)));
typedef short s16x8 __attribute__((ext_vector_type(8)));

__device__ __forceinline__ unsigned int f2bf(float f) {
  // round-to-nearest-even fp32 -> bf16 (inputs finite)
  unsigned int u = __float_as_uint(f);
  u += 0x7FFFu + ((u >> 16) & 1u);
  return u >> 16;
}

__device__ __forceinline__ void stage16(const void* g, void* l) {
  // async global->LDS, 16B/lane; LDS dst = wave-uniform base + lane*16
  __builtin_amdgcn_global_load_lds((const __attribute__((address_space(1))) void*)g,
                                   (__attribute__((address_space(3))) void*)l, 16, 0, 0);
}

// ---------------------------------------------------------------------------
// Prepass: convert X,Y (fp32 [32768][64]) to bf16 packed (uint [32768][32])
// and compute exact fp32 squared norms. 32 threads per row, 2 floats/thread.
// Also zeroes the reduce-phase counter (stream order makes this race-free).
__global__ __launch_bounds__(256)
void prep_kernel(const float* __restrict__ X, const float* __restrict__ Y,
                 unsigned int* __restrict__ Xbf, unsigned int* __restrict__ Ybf,
                 float* __restrict__ x2, float* __restrict__ y2,
                 unsigned int* __restrict__ counter) {
  int gid = blockIdx.x * 256 + threadIdx.x;
  if (gid == 0) *counter = 0;
  int row = gid >> 5;
  int ki  = gid & 31;
  bool isX = row < BATCH * NPTS;
  int r2 = row & (BATCH * NPTS - 1);
  const float* src = isX ? X : Y;
  f32x2 v = *(const f32x2*)(src + (size_t)r2 * KD + ki * 2);
  float s = v[0] * v[0] + v[1] * v[1];
  #pragma unroll
  for (int m = 16; m >= 1; m >>= 1) s += __shfl_xor(s, m, 64);  // stays in 32-lane half
  unsigned int packed = (f2bf(v[1]) << 16) | f2bf(v[0]);
  (isX ? Xbf : Ybf)[r2 * 32 + ki] = packed;
  if (ki == 0) (isX ? x2 : y2)[r2] = s;
}

// ---------------------------------------------------------------------------
// Main: block = (mq, ntile, b). 128 rows x 1024 cols (8 m-tiles of 128).
// Waves in 2x2: wave tile 64x64 per m-tile. launch_bounds(256,2): unified
// reg budget 256 (~128 arch + 128 acc) — a (256,3) cap split 84+84 and
// SPILLED the xf/rm live set to scratch in an earlier session. Live set ~130
// arch fits under 128+granularity.
// WALK=8 (was 4): halves the number of block prologues (X stage + vmcnt(0)
// drain + xf ds_reads amortize over 2x the MFMA work) and halves X re-fetch.
// colpart is flushed per-tt through a 2KB double-buffered l_cred (the tt-end
// barrier makes the cross-rowgroup combine race-free; a buffer half is only
// rewritten one full barrier after it is read), keeping LDS at 50KB ->
// 3 blocks/CU resident.
__global__ __launch_bounds__(256, 2)
void chamfer_main(const unsigned short* __restrict__ Xbf,
                  const unsigned short* __restrict__ Ybf,
                  const float* __restrict__ x2g, const float* __restrict__ y2g,
                  float* __restrict__ rowpart,   // [MQ][B*N] min over strip cols (sq)
                  float* __restrict__ colpart) { // [32][B*M] min over ntile rows (sq)
  __shared__ __align__(16) unsigned short Xs[128 * 64];      // 16 KB (reused as l_redf)
  __shared__ __align__(16) unsigned short Ys[2][128 * 64];   // 32 KB
  __shared__ float l_cred[2 * 2 * 128];                      // 2 KB: [buf][rowgroup][col]

  const int mq = blockIdx.x, ntile = blockIdx.y, b = blockIdx.z;
  const int n0 = ntile * 128;
  const int mbase = mq * (WALK * 128);
  const int t = threadIdx.x, w = t >> 6, lane = t & 63, c = lane & 15, q = lane >> 4;
  const int wr = (w >> 1) * 64, wc = (w & 1) * 64, rg = w >> 1;

  // staging source offset within a 1KB (8-row) block: row=lane>>3, chunk=(lane&7)^(lane>>3)
  const int l8 = lane >> 3;
  const int lane_off = l8 * 128 + (((lane & 7) ^ l8) << 4);

  const char* Xg  = (const char*)(Xbf + (size_t)(b * NPTS + n0) * KD);
  const char* Yg0 = (const char*)(Ybf + (size_t)(b * NPTS + mbase) * KD);

  // Prologue: stage X tile + Y tile 0 (4 x 1KB per wave each)
  #pragma unroll
  for (int k = 0; k < 4; ++k) {
    int blockoff = (k * 32 + w * 8) * 128;
    int ldsoff   = (k * 256 + w * 64) * 16;
    stage16(Xg  + blockoff + lane_off, (char*)Xs    + ldsoff);
    stage16(Yg0 + blockoff + lane_off, (char*)Ys[0] + ldsoff);
  }

  // x2 fragment (rows wr + i*16 + q*4 + r), fp32, L2-hot. 16 VGPRs.
  const float* x2b = x2g + b * NPTS + n0;
  f32x4 x2r[4];
  #pragma unroll
  for (int i = 0; i < 4; ++i) x2r[i] = *(const f32x4*)(x2b + wr + i * 16 + q * 4);

  __syncthreads();  // drains the global_load_lds (vmcnt 0 at barrier)

  // X fragments -> registers (swizzled ds_read_b128, conflict-free). 32 VGPRs.
  const int cx = c & 7;
  s16x8 xf[4][2];
  #pragma unroll
  for (int i = 0; i < 4; ++i)
    #pragma unroll
    for (int ks = 0; ks < 2; ++ks)
      xf[i][ks] = *(const s16x8*)&Xs[(wr + i * 16 + c) * 64 + ((((ks << 2) + q) ^ cx) << 3)];

  float rm[4][4];
  #pragma unroll
  for (int i = 0; i < 4; ++i)
    #pragma unroll
    for (int r = 0; r < 4; ++r) rm[i][r] = FINF;

  const float* y2b = y2g + b * NPTS + mbase;
  float* colrow = colpart + (size_t)(ntile * 8 + b) * NPTS + mbase;
  const f32x4 zacc = {0.f, 0.f, 0.f, 0.f};

  #pragma unroll
  for (int tt = 0; tt < WALK; ++tt) {
    const unsigned short* cur = Ys[tt & 1];

    // y2 for this wave's 4 col groups — issue global loads first (async).
    float y2c[4];
    #pragma unroll
    for (int j = 0; j < 4; ++j) y2c[j] = y2b[tt * 128 + wc + j * 16 + c];

    if (tt < WALK - 1) {  // async-prefetch next Y tile into the other buffer
      const char* Ygt = Yg0 + (size_t)(tt + 1) * 128 * 128;
      unsigned short* nb = Ys[(tt + 1) & 1];
      #pragma unroll
      for (int k = 0; k < 4; ++k)
        stage16(Ygt + (k * 32 + w * 8) * 128 + lane_off,
                (char*)nb + (k * 256 + w * 64) * 16);
    }

    // Flush previous tile's col-mins (combine the 2 rowgroups, add y2, store).
    // l_cred[pb] was written before the barrier that ended tt-1 -> visible;
    // it is next rewritten at the end of THIS tt, i.e. after another barrier.
    if (tt > 0 && t < 128) {
      int pt = tt - 1, pb = pt & 1;
      float v = fminf(l_cred[(pb * 2 + 0) * 128 + t], l_cred[(pb * 2 + 1) * 128 + t]);
      colrow[pt * 128 + t] = v + y2b[pt * 128 + t];
    }

    float cmj[4];
    #pragma unroll
    for (int j = 0; j < 4; ++j) {
      const unsigned short* yrow = &cur[(wc + j * 16 + c) * 64];
      s16x8 yf0 = *(const s16x8*)&yrow[(q ^ cx) << 3];
      s16x8 yf1 = *(const s16x8*)&yrow[((4 + q) ^ cx) << 3];
      f32x4 acc[4];
      #pragma unroll
      for (int i = 0; i < 4; ++i) {
        f32x4 a0 = __builtin_amdgcn_mfma_f32_16x16x32_bf16(xf[i][0], yf0, zacc, 0, 0, 0);
        acc[i] = __builtin_amdgcn_mfma_f32_16x16x32_bf16(xf[i][1], yf1, a0, 0, 0, 0);
      }
      float cm = FINF;
      #pragma unroll
      for (int i = 0; i < 4; ++i)
        #pragma unroll
        for (int r = 0; r < 4; ++r) {
          float v = acc[i][r];
          rm[i][r] = fminf(rm[i][r], fmaf(-2.f, v, y2c[j]));
          cm = fminf(cm, fmaf(-2.f, v, x2r[i][r]));
        }
      // col-min over this wave's 64 rows: reduce across the 4 q-groups
      cm = fminf(cm, __shfl_xor(cm, 16, 64));
      cm = fminf(cm, __shfl_xor(cm, 32, 64));
      cmj[j] = cm;
    }
    // quad q stores col group j==q: one ds_write, 64 consecutive floats/wave
    float cmq = (q == 0) ? cmj[0] : (q == 1) ? cmj[1] : (q == 2) ? cmj[2] : cmj[3];
    l_cred[((tt & 1) * 2 + rg) * 128 + wc + q * 16 + c] = cmq;

    __syncthreads();  // buffer swap barrier (prefetch had MFMA+epilogue to land)
  }

  // Row-min: reduce over the 16 c-lanes within each q-group...
  #pragma unroll
  for (int msk = 1; msk <= 8; msk <<= 1)
    #pragma unroll
    for (int i = 0; i < 4; ++i)
      #pragma unroll
      for (int r = 0; r < 4; ++r)
        rm[i][r] = fminf(rm[i][r], __shfl_xor(rm[i][r], msk, 64));
  // ...then store per-wave row-mins to LDS (literal indices only).
  float* l_redf = (float*)Xs;  // Xs is dead after the prologue xf reads
  if (c == 0) {
    #pragma unroll
    for (int i = 0; i < 4; ++i) {
      f32x4 v = {rm[i][0], rm[i][1], rm[i][2], rm[i][3]};
      *(f32x4*)&l_redf[w * 64 + i * 16 + q * 4] = v;
    }
  }
  __syncthreads();

  if (t < 128) {
    // flush the final tile's col-mins (last loop barrier made them visible)
    {
      int pt = WALK - 1, pb = pt & 1;
      float v = fminf(l_cred[(pb * 2 + 0) * 128 + t], l_cred[(pb * 2 + 1) * 128 + t]);
      colrow[pt * 128 + t] = v + y2b[pt * 128 + t];
    }
    // combine the 2 col-group waves of each row group, add x2, store
    int g = t >> 6, lr = t & 63;
    float v = fminf(l_redf[(g * 2) * 64 + lr], l_redf[(g * 2 + 1) * 64 + lr]);
    rowpart[mq * (BATCH * NPTS) + b * NPTS + n0 + t] = v + x2b[t];
  }
}

// ---------------------------------------------------------------------------
// Final: min over partials, sqrt, mean — self-finalizing (no memset, no 4th
// stream op). 128 blocks; the last block (device-scope ticket) sums the 128
// block partials and writes the scalar output.
__global__ __launch_bounds__(256)
void reduce_kernel(const float* __restrict__ rowpart, const float* __restrict__ colpart,
                   float* __restrict__ partials, unsigned int* __restrict__ counter,
                   float* __restrict__ out) {
  int i = blockIdx.x * 256 + threadIdx.x;
  const int TOT = BATCH * NPTS;
  float rv = FINF;
  #pragma unroll
  for (int s = 0; s < MQ; ++s) rv = fminf(rv, rowpart[s * TOT + i]);
  float s0 = sqrtf(fmaxf(rv, 0.f));
  float cv = FINF;
  #pragma unroll
  for (int nt = 0; nt < 32; ++nt) cv = fminf(cv, colpart[nt * TOT + i]);
  s0 += sqrtf(fmaxf(cv, 0.f));
  #pragma unroll
  for (int m = 32; m >= 1; m >>= 1) s0 += __shfl_xor(s0, m, 64);
  __shared__ float wsum[4];
  if ((threadIdx.x & 63) == 0) wsum[threadIdx.x >> 6] = s0;
  __syncthreads();

  if (threadIdx.x < 64) {  // wave 0 publishes the block partial, then maybe finalizes
    unsigned int ticket = 0;
    if (threadIdx.x == 0) {
      float bsum = wsum[0] + wsum[1] + wsum[2] + wsum[3];
      atomicExch(&partials[blockIdx.x], bsum);  // device-scope visible store
      __threadfence();
      ticket = atomicAdd(counter, 1);
    }
    ticket = __shfl(ticket, 0, 64);
    if (ticket == 127) {  // all 128 partials published
      float v = atomicAdd(&partials[threadIdx.x], 0.0f) +
                atomicAdd(&partials[threadIdx.x + 64], 0.0f);
      #pragma unroll
      for (int m = 32; m >= 1; m >>= 1) v += __shfl_xor(v, m, 64);
      if (threadIdx.x == 0) out[0] = v * (1.0f / (float)TOT);
    }
  }
}

// ---------------------------------------------------------------------------
extern "C" void kernel_launch(void* const* d_in, const int* in_sizes, int n_in,
                              void* d_out, int out_size, void* d_ws, size_t ws_size,
                              hipStream_t stream) {
  const float* X = (const float*)d_in[0];  // [B, N, 64] fp32
  const float* Y = (const float*)d_in[1];  // [B, M, 64] fp32
  float* out = (float*)d_out;

  // Workspace layout (bytes):
  //   Xbf 4MB | Ybf 4MB | x2 128KB | y2 128KB | rowpart 1MB (uses 512KB)
  //   | colpart 4MB | partials 512B | counter 4B
  char* ws = (char*)d_ws;
  unsigned int* Xbf = (unsigned int*)ws;                       // packed bf16 pairs
  unsigned int* Ybf = (unsigned int*)(ws + (4u << 20));
  float* x2 = (float*)(ws + (8u << 20));
  float* y2 = (float*)(ws + (8u << 20) + (128u << 10));
  float* rowpart = (float*)(ws + (8u << 20) + (256u << 10));
  float* colpart = (float*)(ws + (9u << 20) + (256u << 10));
  float* partials = (float*)(ws + (13u << 20) + (256u << 10));
  unsigned int* counter = (unsigned int*)(partials + 128);

  // Prepass: both inputs, 32 threads/row. Also zeroes `counter`.
  prep_kernel<<<dim3(2 * BATCH * NPTS * 32 / 256), dim3(256), 0, stream>>>(
      X, Y, Xbf, Ybf, x2, y2, counter);

  // Main: (mq=4, ntile=32, b=8) = 1024 blocks, 3 resident/CU (LDS 50KB).
  chamfer_main<<<dim3(MQ, 32, 8), dim3(256), 0, stream>>>(
      (const unsigned short*)Xbf, (const unsigned short*)Ybf, x2, y2, rowpart, colpart);

  // Final min/sqrt/mean (self-finalizing via ticket).
  reduce_kernel<<<dim3(BATCH * NPTS / 256), dim3(256), 0, stream>>>(
      rowpart, colpart, partials, counter, out);
}

// Round 3
// 106.770 us; speedup vs baseline: 3.1295x; 3.1295x over previous
//
#include <hip/hip_runtime.h>

// Problem constants (fixed by reference setup_inputs)
#define BATCH 8
#define NPTS  4096   // N == M == 4096
#define KD    64
#define MQ    4      // m-strips: each block walks 1024 cols = 8 tiles of 128
#define WALK  8
#define FINF  3.0e38f

typedef float f32x4 __attribute__((ext_vector_type(4)));
typedef float f32x2 __attribute__((ext_vector_type(2)));
typedef short s16x8 __attribute__((ext_vector_type(8)));

__device__ __forceinline__ unsigned int f2bf(float f) {
  // round-to-nearest-even fp32 -> bf16 (inputs finite)
  unsigned int u = __float_as_uint(f);
  u += 0x7FFFu + ((u >> 16) & 1u);
  return u >> 16;
}

__device__ __forceinline__ void stage16(const void* g, void* l) {
  // async global->LDS, 16B/lane; LDS dst = wave-uniform base + lane*16
  __builtin_amdgcn_global_load_lds((const __attribute__((address_space(1))) void*)g,
                                   (__attribute__((address_space(3))) void*)l, 16, 0, 0);
}

// ---------------------------------------------------------------------------
// Prepass: convert X,Y (fp32 [32768][64]) to bf16 packed (uint [32768][32])
// and compute exact fp32 squared norms. 32 threads per row, 2 floats/thread.
// Also zeroes the reduce-phase counter (stream order makes this race-free).
__global__ __launch_bounds__(256)
void prep_kernel(const float* __restrict__ X, const float* __restrict__ Y,
                 unsigned int* __restrict__ Xbf, unsigned int* __restrict__ Ybf,
                 float* __restrict__ x2, float* __restrict__ y2,
                 unsigned int* __restrict__ counter) {
  int gid = blockIdx.x * 256 + threadIdx.x;
  if (gid == 0) *counter = 0;
  int row = gid >> 5;
  int ki  = gid & 31;
  bool isX = row < BATCH * NPTS;
  int r2 = row & (BATCH * NPTS - 1);
  const float* src = isX ? X : Y;
  f32x2 v = *(const f32x2*)(src + (size_t)r2 * KD + ki * 2);
  float s = v[0] * v[0] + v[1] * v[1];
  #pragma unroll
  for (int m = 16; m >= 1; m >>= 1) s += __shfl_xor(s, m, 64);  // stays in 32-lane half
  unsigned int packed = (f2bf(v[1]) << 16) | f2bf(v[0]);
  (isX ? Xbf : Ybf)[r2 * 32 + ki] = packed;
  if (ki == 0) (isX ? x2 : y2)[r2] = s;
}

// ---------------------------------------------------------------------------
// Main: block = (mq, ntile, b). 128 rows x 1024 cols (8 m-tiles of 128).
// Waves in 2x2: wave tile 64x64 per m-tile. launch_bounds(256,2): unified
// reg budget (~128 arch + ~32 acc) — both LDS (50KB) and VGPR cap at
// 3 blocks/CU.
// WALK=8 halves the number of block prologues (X stage + vmcnt(0) drain +
// xf ds_reads amortize over 2x the MFMA work) and halves X re-fetch.
// *** tt-loop is `#pragma unroll 2`, NOT full: the full 8x unroll let the
// scheduler hoist live ranges across 8 copies and SPILLED (round 2:
// WRITE_SIZE 528MB of scratch, 280us). Two copies keep the tt&1 parity
// indices static while bounding the hoisting window below the proven
// 4-copy baseline. ***
// colpart is flushed per-tt through a 2KB double-buffered l_cred (the tt-end
// barrier makes the cross-rowgroup combine race-free; a buffer half is only
// rewritten one full barrier after it is read).
__global__ __launch_bounds__(256, 2)
void chamfer_main(const unsigned short* __restrict__ Xbf,
                  const unsigned short* __restrict__ Ybf,
                  const float* __restrict__ x2g, const float* __restrict__ y2g,
                  float* __restrict__ rowpart,   // [MQ][B*N] min over strip cols (sq)
                  float* __restrict__ colpart) { // [32][B*M] min over ntile rows (sq)
  __shared__ __align__(16) unsigned short Xs[128 * 64];      // 16 KB (reused as l_redf)
  __shared__ __align__(16) unsigned short Ys[2][128 * 64];   // 32 KB
  __shared__ float l_cred[2 * 2 * 128];                      // 2 KB: [buf][rowgroup][col]

  const int mq = blockIdx.x, ntile = blockIdx.y, b = blockIdx.z;
  const int n0 = ntile * 128;
  const int mbase = mq * (WALK * 128);
  const int t = threadIdx.x, w = t >> 6, lane = t & 63, c = lane & 15, q = lane >> 4;
  const int wr = (w >> 1) * 64, wc = (w & 1) * 64, rg = w >> 1;

  // staging source offset within a 1KB (8-row) block: row=lane>>3, chunk=(lane&7)^(lane>>3)
  const int l8 = lane >> 3;
  const int lane_off = l8 * 128 + (((lane & 7) ^ l8) << 4);

  const char* Xg  = (const char*)(Xbf + (size_t)(b * NPTS + n0) * KD);
  const char* Yg0 = (const char*)(Ybf + (size_t)(b * NPTS + mbase) * KD);

  // Prologue: stage X tile + Y tile 0 (4 x 1KB per wave each)
  #pragma unroll
  for (int k = 0; k < 4; ++k) {
    int blockoff = (k * 32 + w * 8) * 128;
    int ldsoff   = (k * 256 + w * 64) * 16;
    stage16(Xg  + blockoff + lane_off, (char*)Xs    + ldsoff);
    stage16(Yg0 + blockoff + lane_off, (char*)Ys[0] + ldsoff);
  }

  // x2 fragment (rows wr + i*16 + q*4 + r), fp32, L2-hot. 16 VGPRs.
  const float* x2b = x2g + b * NPTS + n0;
  f32x4 x2r[4];
  #pragma unroll
  for (int i = 0; i < 4; ++i) x2r[i] = *(const f32x4*)(x2b + wr + i * 16 + q * 4);

  __syncthreads();  // drains the global_load_lds (vmcnt 0 at barrier)

  // X fragments -> registers (swizzled ds_read_b128, conflict-free). 32 VGPRs.
  const int cx = c & 7;
  s16x8 xf[4][2];
  #pragma unroll
  for (int i = 0; i < 4; ++i)
    #pragma unroll
    for (int ks = 0; ks < 2; ++ks)
      xf[i][ks] = *(const s16x8*)&Xs[(wr + i * 16 + c) * 64 + ((((ks << 2) + q) ^ cx) << 3)];

  float rm[4][4];
  #pragma unroll
  for (int i = 0; i < 4; ++i)
    #pragma unroll
    for (int r = 0; r < 4; ++r) rm[i][r] = FINF;

  const float* y2b = y2g + b * NPTS + mbase;
  float* colrow = colpart + (size_t)(ntile * 8 + b) * NPTS + mbase;
  const f32x4 zacc = {0.f, 0.f, 0.f, 0.f};

  #pragma unroll 2
  for (int tt = 0; tt < WALK; ++tt) {
    const unsigned short* cur = Ys[tt & 1];

    // y2 for this wave's 4 col groups — issue global loads first (async).
    float y2c[4];
    #pragma unroll
    for (int j = 0; j < 4; ++j) y2c[j] = y2b[tt * 128 + wc + j * 16 + c];

    if (tt < WALK - 1) {  // async-prefetch next Y tile into the other buffer
      const char* Ygt = Yg0 + (size_t)(tt + 1) * 128 * 128;
      unsigned short* nb = Ys[(tt + 1) & 1];
      #pragma unroll
      for (int k = 0; k < 4; ++k)
        stage16(Ygt + (k * 32 + w * 8) * 128 + lane_off,
                (char*)nb + (k * 256 + w * 64) * 16);
    }

    // Flush previous tile's col-mins (combine the 2 rowgroups, add y2, store).
    // l_cred[pb] was written before the barrier that ended tt-1 -> visible;
    // it is next rewritten at the end of THIS tt, i.e. after another barrier.
    if (tt > 0 && t < 128) {
      int pt = tt - 1, pb = pt & 1;
      float v = fminf(l_cred[(pb * 2 + 0) * 128 + t], l_cred[(pb * 2 + 1) * 128 + t]);
      colrow[pt * 128 + t] = v + y2b[pt * 128 + t];
    }

    float cmj[4];
    #pragma unroll
    for (int j = 0; j < 4; ++j) {
      const unsigned short* yrow = &cur[(wc + j * 16 + c) * 64];
      s16x8 yf0 = *(const s16x8*)&yrow[(q ^ cx) << 3];
      s16x8 yf1 = *(const s16x8*)&yrow[((4 + q) ^ cx) << 3];
      f32x4 acc[4];
      #pragma unroll
      for (int i = 0; i < 4; ++i) {
        f32x4 a0 = __builtin_amdgcn_mfma_f32_16x16x32_bf16(xf[i][0], yf0, zacc, 0, 0, 0);
        acc[i] = __builtin_amdgcn_mfma_f32_16x16x32_bf16(xf[i][1], yf1, a0, 0, 0, 0);
      }
      float cm = FINF;
      #pragma unroll
      for (int i = 0; i < 4; ++i)
        #pragma unroll
        for (int r = 0; r < 4; ++r) {
          float v = acc[i][r];
          rm[i][r] = fminf(rm[i][r], fmaf(-2.f, v, y2c[j]));
          cm = fminf(cm, fmaf(-2.f, v, x2r[i][r]));
        }
      // col-min over this wave's 64 rows: reduce across the 4 q-groups
      cm = fminf(cm, __shfl_xor(cm, 16, 64));
      cm = fminf(cm, __shfl_xor(cm, 32, 64));
      cmj[j] = cm;
    }
    // quad q stores col group j==q: one ds_write, 64 consecutive floats/wave
    float cmq = (q == 0) ? cmj[0] : (q == 1) ? cmj[1] : (q == 2) ? cmj[2] : cmj[3];
    l_cred[((tt & 1) * 2 + rg) * 128 + wc + q * 16 + c] = cmq;

    __syncthreads();  // buffer swap barrier (prefetch had MFMA+epilogue to land)
  }

  // Row-min: reduce over the 16 c-lanes within each q-group...
  #pragma unroll
  for (int msk = 1; msk <= 8; msk <<= 1)
    #pragma unroll
    for (int i = 0; i < 4; ++i)
      #pragma unroll
      for (int r = 0; r < 4; ++r)
        rm[i][r] = fminf(rm[i][r], __shfl_xor(rm[i][r], msk, 64));
  // ...then store per-wave row-mins to LDS (literal indices only).
  float* l_redf = (float*)Xs;  // Xs is dead after the prologue xf reads
  if (c == 0) {
    #pragma unroll
    for (int i = 0; i < 4; ++i) {
      f32x4 v = {rm[i][0], rm[i][1], rm[i][2], rm[i][3]};
      *(f32x4*)&l_redf[w * 64 + i * 16 + q * 4] = v;
    }
  }
  __syncthreads();

  if (t < 128) {
    // flush the final tile's col-mins (last loop barrier made them visible)
    {
      int pt = WALK - 1, pb = pt & 1;
      float v = fminf(l_cred[(pb * 2 + 0) * 128 + t], l_cred[(pb * 2 + 1) * 128 + t]);
      colrow[pt * 128 + t] = v + y2b[pt * 128 + t];
    }
    // combine the 2 col-group waves of each row group, add x2, store
    int g = t >> 6, lr = t & 63;
    float v = fminf(l_redf[(g * 2) * 64 + lr], l_redf[(g * 2 + 1) * 64 + lr]);
    rowpart[mq * (BATCH * NPTS) + b * NPTS + n0 + t] = v + x2b[t];
  }
}

// ---------------------------------------------------------------------------
// Final: min over partials, sqrt, mean — self-finalizing (no memset, no 4th
// stream op). 128 blocks; the last block (device-scope ticket) sums the 128
// block partials and writes the scalar output.
__global__ __launch_bounds__(256)
void reduce_kernel(const float* __restrict__ rowpart, const float* __restrict__ colpart,
                   float* __restrict__ partials, unsigned int* __restrict__ counter,
                   float* __restrict__ out) {
  int i = blockIdx.x * 256 + threadIdx.x;
  const int TOT = BATCH * NPTS;
  float rv = FINF;
  #pragma unroll
  for (int s = 0; s < MQ; ++s) rv = fminf(rv, rowpart[s * TOT + i]);
  float s0 = sqrtf(fmaxf(rv, 0.f));
  float cv = FINF;
  #pragma unroll
  for (int nt = 0; nt < 32; ++nt) cv = fminf(cv, colpart[nt * TOT + i]);
  s0 += sqrtf(fmaxf(cv, 0.f));
  #pragma unroll
  for (int m = 32; m >= 1; m >>= 1) s0 += __shfl_xor(s0, m, 64);
  __shared__ float wsum[4];
  if ((threadIdx.x & 63) == 0) wsum[threadIdx.x >> 6] = s0;
  __syncthreads();

  if (threadIdx.x < 64) {  // wave 0 publishes the block partial, then maybe finalizes
    unsigned int ticket = 0;
    if (threadIdx.x == 0) {
      float bsum = wsum[0] + wsum[1] + wsum[2] + wsum[3];
      atomicExch(&partials[blockIdx.x], bsum);  // device-scope visible store
      __threadfence();
      ticket = atomicAdd(counter, 1);
    }
    ticket = __shfl(ticket, 0, 64);
    if (ticket == 127) {  // all 128 partials published
      float v = atomicAdd(&partials[threadIdx.x], 0.0f) +
                atomicAdd(&partials[threadIdx.x + 64], 0.0f);
      #pragma unroll
      for (int m = 32; m >= 1; m >>= 1) v += __shfl_xor(v, m, 64);
      if (threadIdx.x == 0) out[0] = v * (1.0f / (float)TOT);
    }
  }
}

// ---------------------------------------------------------------------------
extern "C" void kernel_launch(void* const* d_in, const int* in_sizes, int n_in,
                              void* d_out, int out_size, void* d_ws, size_t ws_size,
                              hipStream_t stream) {
  const float* X = (const float*)d_in[0];  // [B, N, 64] fp32
  const float* Y = (const float*)d_in[1];  // [B, M, 64] fp32
  float* out = (float*)d_out;

  // Workspace layout (bytes):
  //   Xbf 4MB | Ybf 4MB | x2 128KB | y2 128KB | rowpart 1MB (uses 512KB)
  //   | colpart 4MB | partials 512B | counter 4B
  char* ws = (char*)d_ws;
  unsigned int* Xbf = (unsigned int*)ws;                       // packed bf16 pairs
  unsigned int* Ybf = (unsigned int*)(ws + (4u << 20));
  float* x2 = (float*)(ws + (8u << 20));
  float* y2 = (float*)(ws + (8u << 20) + (128u << 10));
  float* rowpart = (float*)(ws + (8u << 20) + (256u << 10));
  float* colpart = (float*)(ws + (9u << 20) + (256u << 10));
  float* partials = (float*)(ws + (13u << 20) + (256u << 10));
  unsigned int* counter = (unsigned int*)(partials + 128);

  // Prepass: both inputs, 32 threads/row. Also zeroes `counter`.
  prep_kernel<<<dim3(2 * BATCH * NPTS * 32 / 256), dim3(256), 0, stream>>>(
      X, Y, Xbf, Ybf, x2, y2, counter);

  // Main: (mq=4, ntile=32, b=8) = 1024 blocks, 3 resident/CU (LDS 50KB).
  chamfer_main<<<dim3(MQ, 32, 8), dim3(256), 0, stream>>>(
      (const unsigned short*)Xbf, (const unsigned short*)Ybf, x2, y2, rowpart, colpart);

  // Final min/sqrt/mean (self-finalizing via ticket).
  reduce_kernel<<<dim3(BATCH * NPTS / 256), dim3(256), 0, stream>>>(
      rowpart, colpart, partials, counter, out);
}

// Round 4
// 104.457 us; speedup vs baseline: 3.1988x; 1.0221x over previous
//
#include <hip/hip_runtime.h>

// Problem constants (fixed by reference setup_inputs)
#define BATCH 8
#define NPTS  4096   // N == M == 4096
#define KD    64
#define MQ    4      // m-strips: each block walks 1024 cols = 8 tiles of 128
#define WALK  8
#define FINF  3.0e38f

typedef float f32x4 __attribute__((ext_vector_type(4)));
typedef float f32x2 __attribute__((ext_vector_type(2)));
typedef short s16x8 __attribute__((ext_vector_type(8)));

__device__ __forceinline__ unsigned int f2bf(float f) {
  // round-to-nearest-even fp32 -> bf16 (inputs finite)
  unsigned int u = __float_as_uint(f);
  u += 0x7FFFu + ((u >> 16) & 1u);
  return u >> 16;
}

__device__ __forceinline__ void stage16(const void* g, void* l) {
  // async global->LDS, 16B/lane; LDS dst = wave-uniform base + lane*16
  __builtin_amdgcn_global_load_lds((const __attribute__((address_space(1))) void*)g,
                                   (__attribute__((address_space(3))) void*)l, 16, 0, 0);
}

// ---------------------------------------------------------------------------
// Prepass: convert X,Y (fp32 [32768][64]) to bf16 packed (uint [32768][32])
// and compute exact fp32 squared norms. 32 threads per row, 2 floats/thread.
// Also zeroes the reduce-phase counter (stream order makes this race-free).
__global__ __launch_bounds__(256)
void prep_kernel(const float* __restrict__ X, const float* __restrict__ Y,
                 unsigned int* __restrict__ Xbf, unsigned int* __restrict__ Ybf,
                 float* __restrict__ x2, float* __restrict__ y2,
                 unsigned int* __restrict__ counter) {
  int gid = blockIdx.x * 256 + threadIdx.x;
  if (gid == 0) *counter = 0;
  int row = gid >> 5;
  int ki  = gid & 31;
  bool isX = row < BATCH * NPTS;
  int r2 = row & (BATCH * NPTS - 1);
  const float* src = isX ? X : Y;
  f32x2 v = *(const f32x2*)(src + (size_t)r2 * KD + ki * 2);
  float s = v[0] * v[0] + v[1] * v[1];
  #pragma unroll
  for (int m = 16; m >= 1; m >>= 1) s += __shfl_xor(s, m, 64);  // stays in 32-lane half
  unsigned int packed = (f2bf(v[1]) << 16) | f2bf(v[0]);
  (isX ? Xbf : Ybf)[r2 * 32 + ki] = packed;
  if (ki == 0) (isX ? x2 : y2)[r2] = s;
}

// ---------------------------------------------------------------------------
// Main: block = (mq, ntile, b). 128 rows x 1024 cols (8 m-tiles of 128).
// Waves in 2x2: wave tile 64x64 per m-tile.
// OCCUPANCY ROUND: X is no longer LDS-staged — xf fragments are gathered
// straight from global in the prologue (read once per block; L2/LLC-hot;
// 8 dwordx4 per wave at 16-rows-x-64B granularity). LDS drops 50->37 KB ->
// 4 blocks/CU resident (16 waves, +33% latency hiding). 1024 blocks = exactly
// 4/CU, one co-resident set. The j-loop's cross-lane col-reduce is cut from
// two serial __shfl_xor to ONE (q-pair reduce); the remaining 4 partials per
// col go through a padded l_credq (stride 132 breaks the x128 bank alias)
// and are combined in the per-tt flush.
// tt-loop stays `#pragma unroll 2` (full 8x unroll spilled in round 2:
// 528MB scratch). launch_bounds(256,2): compiler landed at 128 VGPR here —
// exactly the 4-blocks/CU cap. (256,4) would force an 64+64 arch/acc split
// and spill (see (256,3) history note).
__global__ __launch_bounds__(256, 2)
void chamfer_main(const unsigned short* __restrict__ Xbf,
                  const unsigned short* __restrict__ Ybf,
                  const float* __restrict__ x2g, const float* __restrict__ y2g,
                  float* __restrict__ rowpart,   // [MQ][B*N] min over strip cols (sq)
                  float* __restrict__ colpart) { // [32][B*M] min over ntile rows (sq)
  __shared__ __align__(16) unsigned short Ys[2][128 * 64];   // 32 KB
  __shared__ float l_credq[2 * 4 * 132];                     // 4.1 KB, +4 pad vs banks
  __shared__ float l_redf[256];                              // 1 KB

  const int mq = blockIdx.x, ntile = blockIdx.y, b = blockIdx.z;
  const int n0 = ntile * 128;
  const int mbase = mq * (WALK * 128);
  const int t = threadIdx.x, w = t >> 6, lane = t & 63, c = lane & 15, q = lane >> 4;
  const int wr = (w >> 1) * 64, wc = (w & 1) * 64, rg = w >> 1;

  // staging source offset within a 1KB (8-row) block: row=lane>>3, chunk=(lane&7)^(lane>>3)
  const int l8 = lane >> 3;
  const int lane_off = l8 * 128 + (((lane & 7) ^ l8) << 4);

  const unsigned short* Xrow = Xbf + (size_t)(b * NPTS + n0) * KD;  // [128][64] bf16
  const char* Yg0 = (const char*)(Ybf + (size_t)(b * NPTS + mbase) * KD);

  // Prologue: stage Y tile 0 (4 x 1KB per wave)
  #pragma unroll
  for (int k = 0; k < 4; ++k)
    stage16(Yg0 + (k * 32 + w * 8) * 128 + lane_off,
            (char*)Ys[0] + (k * 256 + w * 64) * 16);

  // X fragments straight from global (once per block). Lane (q,c) reads rows
  // wr+i*16+c, k-chunk (ks*4+q)*8 — per instr: 16 rows x 64B segments. 32 VGPRs.
  s16x8 xf[4][2];
  #pragma unroll
  for (int i = 0; i < 4; ++i)
    #pragma unroll
    for (int ks = 0; ks < 2; ++ks)
      xf[i][ks] = *(const s16x8*)&Xrow[(size_t)(wr + i * 16 + c) * KD + (ks * 4 + q) * 8];

  // x2 fragment (rows wr + i*16 + q*4 + r), fp32, L2-hot. 16 VGPRs.
  const float* x2b = x2g + b * NPTS + n0;
  f32x4 x2r[4];
  #pragma unroll
  for (int i = 0; i < 4; ++i) x2r[i] = *(const f32x4*)(x2b + wr + i * 16 + q * 4);

  __syncthreads();  // drains the Y0 global_load_lds (vmcnt 0 at barrier)

  float rm[4][4];
  #pragma unroll
  for (int i = 0; i < 4; ++i)
    #pragma unroll
    for (int r = 0; r < 4; ++r) rm[i][r] = FINF;

  const int cx = c & 7;
  const float* y2b = y2g + b * NPTS + mbase;
  float* colrow = colpart + (size_t)(ntile * 8 + b) * NPTS + mbase;
  const f32x4 zacc = {0.f, 0.f, 0.f, 0.f};

  #pragma unroll 2
  for (int tt = 0; tt < WALK; ++tt) {
    const unsigned short* cur = Ys[tt & 1];

    // y2 for this wave's 4 col groups — issue global loads first (async).
    float y2c[4];
    #pragma unroll
    for (int j = 0; j < 4; ++j) y2c[j] = y2b[tt * 128 + wc + j * 16 + c];

    if (tt < WALK - 1) {  // async-prefetch next Y tile into the other buffer
      const char* Ygt = Yg0 + (size_t)(tt + 1) * 128 * 128;
      unsigned short* nb = Ys[(tt + 1) & 1];
      #pragma unroll
      for (int k = 0; k < 4; ++k)
        stage16(Ygt + (k * 32 + w * 8) * 128 + lane_off,
                (char*)nb + (k * 256 + w * 64) * 16);
    }

    // Flush previous tile's col-mins (combine 4 q-pair/rowgroup partials,
    // add y2, store). l_credq[pb] was written before the barrier that ended
    // tt-1 -> visible; it is rewritten only after the barrier ending THIS tt.
    if (tt > 0 && t < 128) {
      int pt = tt - 1, pb = pt & 1;
      float v = fminf(fminf(l_credq[(pb * 4 + 0) * 132 + t], l_credq[(pb * 4 + 1) * 132 + t]),
                      fminf(l_credq[(pb * 4 + 2) * 132 + t], l_credq[(pb * 4 + 3) * 132 + t]));
      colrow[pt * 128 + t] = v + y2b[pt * 128 + t];
    }

    float cmj[4];
    #pragma unroll
    for (int j = 0; j < 4; ++j) {
      const unsigned short* yrow = &cur[(wc + j * 16 + c) * 64];
      s16x8 yf0 = *(const s16x8*)&yrow[(q ^ cx) << 3];
      s16x8 yf1 = *(const s16x8*)&yrow[((4 + q) ^ cx) << 3];
      f32x4 acc[4];
      #pragma unroll
      for (int i = 0; i < 4; ++i) {
        f32x4 a0 = __builtin_amdgcn_mfma_f32_16x16x32_bf16(xf[i][0], yf0, zacc, 0, 0, 0);
        acc[i] = __builtin_amdgcn_mfma_f32_16x16x32_bf16(xf[i][1], yf1, a0, 0, 0, 0);
      }
      float cm = FINF;
      #pragma unroll
      for (int i = 0; i < 4; ++i)
        #pragma unroll
        for (int r = 0; r < 4; ++r) {
          float v = acc[i][r];
          rm[i][r] = fminf(rm[i][r], fmaf(-2.f, v, y2c[j]));
          cm = fminf(cm, fmaf(-2.f, v, x2r[i][r]));
        }
      // ONE cross-lane step: combine q-pairs {0,1} and {2,3}
      cm = fminf(cm, __shfl_xor(cm, 16, 64));
      cmj[j] = cm;
    }
    // Each lane stores 2 of the (q-half, j) partials: q&1 picks the j-pair,
    // q>>1 picks the row-half slot. Addr stride 132 breaks the x128 bank alias.
    {
      int s = rg * 2 + (q >> 1);
      int jA = (q & 1) * 2;
      float sA = (q & 1) ? cmj[2] : cmj[0];
      float sB = (q & 1) ? cmj[3] : cmj[1];
      float* dst = &l_credq[((tt & 1) * 4 + s) * 132 + wc + c];
      dst[jA * 16]      = sA;
      dst[jA * 16 + 16] = sB;
    }

    __syncthreads();  // buffer swap barrier (prefetch had MFMA+epilogue to land)
  }

  // Row-min: reduce over the 16 c-lanes within each q-group...
  #pragma unroll
  for (int msk = 1; msk <= 8; msk <<= 1)
    #pragma unroll
    for (int i = 0; i < 4; ++i)
      #pragma unroll
      for (int r = 0; r < 4; ++r)
        rm[i][r] = fminf(rm[i][r], __shfl_xor(rm[i][r], msk, 64));
  // ...then store per-wave row-mins to LDS (literal indices only).
  if (c == 0) {
    #pragma unroll
    for (int i = 0; i < 4; ++i) {
      f32x4 v = {rm[i][0], rm[i][1], rm[i][2], rm[i][3]};
      *(f32x4*)&l_redf[w * 64 + i * 16 + q * 4] = v;
    }
  }
  __syncthreads();

  if (t < 128) {
    // flush the final tile's col-mins (last loop barrier made them visible)
    {
      int pt = WALK - 1, pb = pt & 1;
      float v = fminf(fminf(l_credq[(pb * 4 + 0) * 132 + t], l_credq[(pb * 4 + 1) * 132 + t]),
                      fminf(l_credq[(pb * 4 + 2) * 132 + t], l_credq[(pb * 4 + 3) * 132 + t]));
      colrow[pt * 128 + t] = v + y2b[pt * 128 + t];
    }
    // combine the 2 col-group waves of each row group, add x2, store
    int g = t >> 6, lr = t & 63;
    float v = fminf(l_redf[(g * 2) * 64 + lr], l_redf[(g * 2 + 1) * 64 + lr]);
    rowpart[mq * (BATCH * NPTS) + b * NPTS + n0 + t] = v + x2b[t];
  }
}

// ---------------------------------------------------------------------------
// Final: min over partials, sqrt, mean — self-finalizing (no memset, no 4th
// stream op). 128 blocks; the last block (device-scope ticket) sums the 128
// block partials and writes the scalar output.
__global__ __launch_bounds__(256)
void reduce_kernel(const float* __restrict__ rowpart, const float* __restrict__ colpart,
                   float* __restrict__ partials, unsigned int* __restrict__ counter,
                   float* __restrict__ out) {
  int i = blockIdx.x * 256 + threadIdx.x;
  const int TOT = BATCH * NPTS;
  float rv = FINF;
  #pragma unroll
  for (int s = 0; s < MQ; ++s) rv = fminf(rv, rowpart[s * TOT + i]);
  float s0 = sqrtf(fmaxf(rv, 0.f));
  float cv = FINF;
  #pragma unroll
  for (int nt = 0; nt < 32; ++nt) cv = fminf(cv, colpart[nt * TOT + i]);
  s0 += sqrtf(fmaxf(cv, 0.f));
  #pragma unroll
  for (int m = 32; m >= 1; m >>= 1) s0 += __shfl_xor(s0, m, 64);
  __shared__ float wsum[4];
  if ((threadIdx.x & 63) == 0) wsum[threadIdx.x >> 6] = s0;
  __syncthreads();

  if (threadIdx.x < 64) {  // wave 0 publishes the block partial, then maybe finalizes
    unsigned int ticket = 0;
    if (threadIdx.x == 0) {
      float bsum = wsum[0] + wsum[1] + wsum[2] + wsum[3];
      atomicExch(&partials[blockIdx.x], bsum);  // device-scope visible store
      __threadfence();
      ticket = atomicAdd(counter, 1);
    }
    ticket = __shfl(ticket, 0, 64);
    if (ticket == 127) {  // all 128 partials published
      float v = atomicAdd(&partials[threadIdx.x], 0.0f) +
                atomicAdd(&partials[threadIdx.x + 64], 0.0f);
      #pragma unroll
      for (int m = 32; m >= 1; m >>= 1) v += __shfl_xor(v, m, 64);
      if (threadIdx.x == 0) out[0] = v * (1.0f / (float)TOT);
    }
  }
}

// ---------------------------------------------------------------------------
extern "C" void kernel_launch(void* const* d_in, const int* in_sizes, int n_in,
                              void* d_out, int out_size, void* d_ws, size_t ws_size,
                              hipStream_t stream) {
  const float* X = (const float*)d_in[0];  // [B, N, 64] fp32
  const float* Y = (const float*)d_in[1];  // [B, M, 64] fp32
  float* out = (float*)d_out;

  // Workspace layout (bytes):
  //   Xbf 4MB | Ybf 4MB | x2 128KB | y2 128KB | rowpart 1MB (uses 512KB)
  //   | colpart 4MB | partials 512B | counter 4B
  char* ws = (char*)d_ws;
  unsigned int* Xbf = (unsigned int*)ws;                       // packed bf16 pairs
  unsigned int* Ybf = (unsigned int*)(ws + (4u << 20));
  float* x2 = (float*)(ws + (8u << 20));
  float* y2 = (float*)(ws + (8u << 20) + (128u << 10));
  float* rowpart = (float*)(ws + (8u << 20) + (256u << 10));
  float* colpart = (float*)(ws + (9u << 20) + (256u << 10));
  float* partials = (float*)(ws + (13u << 20) + (256u << 10));
  unsigned int* counter = (unsigned int*)(partials + 128);

  // Prepass: both inputs, 32 threads/row. Also zeroes `counter`.
  prep_kernel<<<dim3(2 * BATCH * NPTS * 32 / 256), dim3(256), 0, stream>>>(
      X, Y, Xbf, Ybf, x2, y2, counter);

  // Main: (mq=4, ntile=32, b=8) = 1024 blocks, 4 resident/CU (LDS 37KB).
  chamfer_main<<<dim3(MQ, 32, 8), dim3(256), 0, stream>>>(
      (const unsigned short*)Xbf, (const unsigned short*)Ybf, x2, y2, rowpart, colpart);

  // Final min/sqrt/mean (self-finalizing via ticket).
  reduce_kernel<<<dim3(BATCH * NPTS / 256), dim3(256), 0, stream>>>(
      rowpart, colpart, partials, counter, out);
}